// Round 1
// baseline (546.315 us; speedup 1.0000x reference)
//
#include <hip/hip_runtime.h>

#define NBATCH   1000000
#define NBLOCKS  15625      // NBATCH / 64
#define EPB      64         // elements (= threads) per block

// ---- async global -> LDS, 16B per lane -------------------------------------
__device__ __forceinline__ void g2l16(const float* g, float* l) {
    __builtin_amdgcn_global_load_lds(
        (const __attribute__((address_space(1))) void*)g,
        (__attribute__((address_space(3))) void*)l,
        16, 0, 0);
}

// copy n4 float4-chunks from contiguous global region g into LDS l.
// Lane i handles chunk i, i+64, ... ; LDS dest base is wave-uniform per iter.
__device__ __forceinline__ void stage_region(const float* __restrict__ g,
                                             float* l, int n4, int lane) {
    for (int i = lane; i < n4; i += 64) {
        g2l16(g + 4 * i, l + 4 * (i - lane));   // i - lane == iter*64 (uniform)
    }
}

__global__ __launch_bounds__(EPB) void
fused_grad_kernel(const float* __restrict__ R1g, const float* __restrict__ R2g,
                  const float* __restrict__ t1g, const float* __restrict__ t2g,
                  const float* __restrict__ f1g, const float* __restrict__ f2g,
                  const float* __restrict__ Wg,
                  float* __restrict__ out, float* __restrict__ partial) {
    // LDS staging buffers (27,392 B total -> 5 blocks/CU)
    __shared__ __align__(16) float sW [EPB * 81];  // 20736 B (reused for outputs)
    __shared__ __align__(16) float sR1[EPB * 9];
    __shared__ __align__(16) float sR2[EPB * 9];
    __shared__ __align__(16) float sT1[EPB * 3];
    __shared__ __align__(16) float sT2[EPB * 3];
    __shared__ __align__(16) float sF1[EPB];
    __shared__ __align__(16) float sF2[EPB];

    const int lane = threadIdx.x;
    const int blk  = blockIdx.x;
    const size_t e0 = (size_t)blk * EPB;

    stage_region(Wg  + e0 * 81, sW , EPB * 81 / 4, lane);  // 1296 chunks
    stage_region(R1g + e0 * 9 , sR1, EPB * 9  / 4, lane);
    stage_region(R2g + e0 * 9 , sR2, EPB * 9  / 4, lane);
    stage_region(t1g + e0 * 3 , sT1, EPB * 3  / 4, lane);
    stage_region(t2g + e0 * 3 , sT2, EPB * 3  / 4, lane);
    stage_region(f1g + e0     , sF1, EPB      / 4, lane);
    stage_region(f2g + e0     , sF2, EPB      / 4, lane);
    __syncthreads();   // drains vmcnt (global_load_lds) + barrier

    // ---- per-element registers ----
    float r1[9], r2[9];
#pragma unroll
    for (int k = 0; k < 9; ++k) { r1[k] = sR1[lane * 9 + k]; r2[k] = sR2[lane * 9 + k]; }
    const float x1 = sT1[lane * 3 + 0], y1 = sT1[lane * 3 + 1], w1 = sT1[lane * 3 + 2];
    const float x2 = sT2[lane * 3 + 0], y2 = sT2[lane * 3 + 1], w2 = sT2[lane * 3 + 2];
    const float a1 = sF1[lane], a2 = sF2[lane];

    // R_rel = R2 @ R1^T
    float Rr[9];
#pragma unroll
    for (int i = 0; i < 3; ++i)
#pragma unroll
        for (int j = 0; j < 3; ++j)
            Rr[i * 3 + j] = r2[i * 3 + 0] * r1[j * 3 + 0]
                          + r2[i * 3 + 1] * r1[j * 3 + 1]
                          + r2[i * 3 + 2] * r1[j * 3 + 2];

    // E = Rr @ t1x - t2x @ Rr ; t1x/t2x = skew((x,y,w))
    float E[9];
#pragma unroll
    for (int i = 0; i < 3; ++i) {
        E[i * 3 + 0] = Rr[i * 3 + 1] * w1 - Rr[i * 3 + 2] * y1;
        E[i * 3 + 1] = Rr[i * 3 + 2] * x1 - Rr[i * 3 + 0] * w1;
        E[i * 3 + 2] = Rr[i * 3 + 0] * y1 - Rr[i * 3 + 1] * x1;
    }
#pragma unroll
    for (int j = 0; j < 3; ++j) {
        E[0 * 3 + j] -= (y2 * Rr[2 * 3 + j] - w2 * Rr[1 * 3 + j]);
        E[1 * 3 + j] -= (w2 * Rr[0 * 3 + j] - x2 * Rr[2 * 3 + j]);
        E[2 * 3 + j] -= (x2 * Rr[1 * 3 + j] - y2 * Rr[0 * 3 + j]);
    }

    const float k1v[3] = {a1, a1, 1.0f};
    const float k2v[3] = {a2, a2, 1.0f};

    // F = k2[i] * E * k1[j]; normalize
    float Fh[9];
    float ss = 0.0f;
#pragma unroll
    for (int i = 0; i < 3; ++i)
#pragma unroll
        for (int j = 0; j < 3; ++j) {
            const float v = k2v[i] * E[i * 3 + j] * k1v[j];
            Fh[i * 3 + j] = v;
            ss += v * v;
        }
    const float nrm   = sqrtf(ss) + 1e-8f;
    const float inv_n = 1.0f / nrm;
#pragma unroll
    for (int k = 0; k < 9; ++k) Fh[k] *= inv_n;

    // W_vec = W @ Fh  (81 LDS reads, stride 81 -> only 2-way bank alias, free)
    float wv[9];
    const int wbase = lane * 81;
#pragma unroll
    for (int i = 0; i < 9; ++i) {
        float acc = 0.0f;
#pragma unroll
        for (int j = 0; j < 9; ++j) acc += sW[wbase + i * 9 + j] * Fh[j];
        wv[i] = acc;
    }

    float s2 = 0.0f;
#pragma unroll
    for (int k = 0; k < 9; ++k) s2 += Fh[k] * wv[k];

    // dF = (wv - s2*Fh)/n
    float dF[9];
#pragma unroll
    for (int k = 0; k < 9; ++k) dF[k] = (wv[k] - s2 * Fh[k]) * inv_n;

    // dE, d_f1, d_f2
    float dE[9];
    float df1 = 0.0f, df2 = 0.0f;
#pragma unroll
    for (int i = 0; i < 3; ++i)
#pragma unroll
        for (int j = 0; j < 3; ++j) {
            const float d  = dF[i * 3 + j];
            dE[i * 3 + j]  = d * k2v[i] * k1v[j];
            const float de = d * E[i * 3 + j];
            if (j < 2) df1 += de * k2v[i];
            if (i < 2) df2 += de * k1v[j];
        }

    // d_Rr = t2x @ dE - dE @ t1x   (skew^T = -skew)
    float dRr[9];
#pragma unroll
    for (int i = 0; i < 3; ++i) {
        dRr[i * 3 + 0] = -(dE[i * 3 + 1] * w1 - dE[i * 3 + 2] * y1);
        dRr[i * 3 + 1] = -(dE[i * 3 + 2] * x1 - dE[i * 3 + 0] * w1);
        dRr[i * 3 + 2] = -(dE[i * 3 + 0] * y1 - dE[i * 3 + 1] * x1);
    }
#pragma unroll
    for (int j = 0; j < 3; ++j) {
        dRr[0 * 3 + j] += y2 * dE[2 * 3 + j] - w2 * dE[1 * 3 + j];
        dRr[1 * 3 + j] += w2 * dE[0 * 3 + j] - x2 * dE[2 * 3 + j];
        dRr[2 * 3 + j] += x2 * dE[1 * 3 + j] - y2 * dE[0 * 3 + j];
    }

    // d_t1 from d_t1x = Rr^T dE ; d_t2 from d_t2x = -dE Rr^T
    float dt1_0 = 0, dt1_1 = 0, dt1_2 = 0, dt2_0 = 0, dt2_1 = 0, dt2_2 = 0;
#pragma unroll
    for (int k = 0; k < 3; ++k) {
        dt1_0 += Rr[k * 3 + 2] * dE[k * 3 + 1] - Rr[k * 3 + 1] * dE[k * 3 + 2];
        dt1_1 += Rr[k * 3 + 0] * dE[k * 3 + 2] - Rr[k * 3 + 2] * dE[k * 3 + 0];
        dt1_2 += Rr[k * 3 + 1] * dE[k * 3 + 0] - Rr[k * 3 + 0] * dE[k * 3 + 1];
        dt2_0 += dE[1 * 3 + k] * Rr[2 * 3 + k] - dE[2 * 3 + k] * Rr[1 * 3 + k];
        dt2_1 += dE[2 * 3 + k] * Rr[0 * 3 + k] - dE[0 * 3 + k] * Rr[2 * 3 + k];
        dt2_2 += dE[0 * 3 + k] * Rr[1 * 3 + k] - dE[1 * 3 + k] * Rr[0 * 3 + k];
    }

    // d_R1 = dRr^T @ R2 ; d_R2 = dRr @ R1
    float dR1[9], dR2[9];
#pragma unroll
    for (int i = 0; i < 3; ++i)
#pragma unroll
        for (int j = 0; j < 3; ++j) {
            dR1[i * 3 + j] = dRr[0 * 3 + i] * r2[0 * 3 + j]
                           + dRr[1 * 3 + i] * r2[1 * 3 + j]
                           + dRr[2 * 3 + i] * r2[2 * 3 + j];
            dR2[i * 3 + j] = dRr[i * 3 + 0] * r1[0 * 3 + j]
                           + dRr[i * 3 + 1] * r1[1 * 3 + j]
                           + dRr[i * 3 + 2] * r1[2 * 3 + j];
        }

    // per-wave loss reduce -> one partial per block (no atomics)
    float lv = 0.5f * s2;
#pragma unroll
    for (int off = 32; off > 0; off >>= 1) lv += __shfl_down(lv, off, 64);
    if (lane == 0) partial[blk] = lv;

    // ---- stage outputs in LDS (reuse sW), then coalesced dword stores ----
    __syncthreads();   // all lanes done reading sW
    float* sOut = sW;  // needs 1664 floats, sW has 5184
#pragma unroll
    for (int k = 0; k < 9; ++k) {
        sOut[lane * 9 + k]       = dR1[k];
        sOut[576 + lane * 9 + k] = dR2[k];
    }
    sOut[1152 + lane * 3 + 0] = dt1_0;
    sOut[1152 + lane * 3 + 1] = dt1_1;
    sOut[1152 + lane * 3 + 2] = dt1_2;
    sOut[1344 + lane * 3 + 0] = dt2_0;
    sOut[1344 + lane * 3 + 1] = dt2_1;
    sOut[1344 + lane * 3 + 2] = dt2_2;
    sOut[1536 + lane] = df1;
    sOut[1600 + lane] = df2;
    __syncthreads();

    const size_t Bc = NBATCH;
    float* oBase = out + 1;                 // out[0] is the loss scalar
    float* oR1 = oBase + e0 * 9;
    float* oR2 = oBase + Bc * 9  + e0 * 9;
    float* oT1 = oBase + Bc * 18 + e0 * 3;
    float* oT2 = oBase + Bc * 21 + e0 * 3;
    float* oF1 = oBase + Bc * 24 + e0;
    float* oF2 = oBase + Bc * 25 + e0;
#pragma unroll
    for (int it = 0; it < 9; ++it) {
        const int i = it * 64 + lane;
        oR1[i] = sOut[i];
        oR2[i] = sOut[576 + i];
    }
#pragma unroll
    for (int it = 0; it < 3; ++it) {
        const int i = it * 64 + lane;
        oT1[i] = sOut[1152 + i];
        oT2[i] = sOut[1344 + i];
    }
    oF1[lane] = sOut[1536 + lane];
    oF2[lane] = sOut[1600 + lane];
}

// reduce 15625 per-block partials (in double) -> out[0]
__global__ __launch_bounds__(256) void
finalize_kernel(const float* __restrict__ partial, float* __restrict__ out) {
    __shared__ double sd[256];
    double acc = 0.0;
    for (int i = threadIdx.x; i < NBLOCKS; i += 256) acc += (double)partial[i];
    sd[threadIdx.x] = acc;
    __syncthreads();
    for (int s = 128; s > 0; s >>= 1) {
        if (threadIdx.x < s) sd[threadIdx.x] += sd[threadIdx.x + s];
        __syncthreads();
    }
    if (threadIdx.x == 0) out[0] = (float)sd[0];
}

extern "C" void kernel_launch(void* const* d_in, const int* in_sizes, int n_in,
                              void* d_out, int out_size, void* d_ws, size_t ws_size,
                              hipStream_t stream) {
    const float* R1 = (const float*)d_in[0];
    const float* R2 = (const float*)d_in[1];
    const float* t1 = (const float*)d_in[2];
    const float* t2 = (const float*)d_in[3];
    const float* f1 = (const float*)d_in[4];
    const float* f2 = (const float*)d_in[5];
    const float* W  = (const float*)d_in[6];
    float* out     = (float*)d_out;
    float* partial = (float*)d_ws;   // NBLOCKS floats, fully rewritten each call

    fused_grad_kernel<<<NBLOCKS, EPB, 0, stream>>>(R1, R2, t1, t2, f1, f2, W,
                                                   out, partial);
    finalize_kernel<<<1, 256, 0, stream>>>(partial, out);
}